// Round 1
// baseline (1300.072 us; speedup 1.0000x reference)
//
#include <hip/hip_runtime.h>
#include <hip/hip_bf16.h>
#include <stdint.h>

#define D_MODEL 1024
#define NHEAD 16
#define DKH 64
#define D_FF 4096
#define BATCH 2
#define SEQ 2048
#define MROWS (BATCH*SEQ)   /* 4096 */
#define BHT (BATCH*NHEAD)   /* 32 */
#define LN_EPS 1e-5f

typedef __attribute__((ext_vector_type(8))) __bf16 bf16x8;
typedef __attribute__((ext_vector_type(4))) float f32x4;

__device__ __forceinline__ unsigned short f2b(float f) {
    union { float f; unsigned int u; } x; x.f = f;
    unsigned int r = x.u + 0x7fffu + ((x.u >> 16) & 1u);
    return (unsigned short)(r >> 16);
}

__device__ __forceinline__ void gload_lds16(const void* g, void* l) {
    __builtin_amdgcn_global_load_lds(
        (const __attribute__((address_space(1))) unsigned int*)g,
        (__attribute__((address_space(3))) unsigned int*)l, 16, 0, 0);
}

// ---------------- fp32 -> bf16 convert (contiguous) ----------------
__global__ void cvt_f32_bf16(const float* __restrict__ in,
                             unsigned short* __restrict__ out, int n4) {
    int i = blockIdx.x * blockDim.x + threadIdx.x;
    if (i < n4) {
        float4 v = ((const float4*)in)[i];
        ushort4 o; o.x = f2b(v.x); o.y = f2b(v.y); o.z = f2b(v.z); o.w = f2b(v.w);
        ((ushort4*)out)[i] = o;
    }
}

// ---------------- fp32 [R,C] -> bf16 [C,R] transpose ----------------
__global__ void tr_f32_bf16(const float* __restrict__ in,
                            unsigned short* __restrict__ out, int R, int C) {
    __shared__ float tile[32][33];
    int tx = threadIdx.x & 31, ty = threadIdx.x >> 5; // ty 0..7
    int r0 = blockIdx.y * 32, c0 = blockIdx.x * 32;
#pragma unroll
    for (int i = 0; i < 4; i++) {
        int r = ty + i * 8;
        tile[r][tx] = in[(size_t)(r0 + r) * C + c0 + tx];
    }
    __syncthreads();
#pragma unroll
    for (int i = 0; i < 4; i++) {
        int r = ty + i * 8;
        out[(size_t)(c0 + r) * R + r0 + tx] = f2b(tile[tx][r]);
    }
}

// ---------------- v [B*S, D] bf16 -> vt [B][D][S] bf16 --------------
__global__ void tr_v(const unsigned short* __restrict__ v,
                     unsigned short* __restrict__ vt) {
    __shared__ unsigned short tile[32][33];
    int b = blockIdx.z;
    const unsigned short* in = v + (size_t)b * SEQ * D_MODEL;
    unsigned short* out = vt + (size_t)b * D_MODEL * SEQ;
    int tx = threadIdx.x & 31, ty = threadIdx.x >> 5;
    int r0 = blockIdx.y * 32, c0 = blockIdx.x * 32; // r over SEQ, c over D
#pragma unroll
    for (int i = 0; i < 4; i++) {
        int r = ty + i * 8;
        tile[r][tx] = in[(size_t)(r0 + r) * D_MODEL + c0 + tx];
    }
    __syncthreads();
#pragma unroll
    for (int i = 0; i < 4; i++) {
        int r = ty + i * 8;
        out[(size_t)(c0 + r) * SEQ + r0 + tx] = tile[tx][r];
    }
}

// ---------------- generic bf16 GEMM: C = A @ Bt^T + bias ------------
// A [M,K] bf16 row-major (lda=K), Bt [N,K] bf16 row-major (ldb=K).
// 128x128 tile, 4 waves 2x2, 16x16x32 MFMA, global_load_lds staging.
template<bool OUT_BF, bool RELU>
__global__ void gemm_bf16(const unsigned short* __restrict__ A,
                          const unsigned short* __restrict__ Bt,
                          const float* __restrict__ bias,
                          float* __restrict__ Cf,
                          unsigned short* __restrict__ Cb,
                          int Msz, int Nsz, int Ksz) {
    __shared__ unsigned short sA[128 * 32];
    __shared__ unsigned short sB[128 * 32];
    int tid = threadIdx.x;
    int lane = tid & 63, wid = tid >> 6;
    int wr = wid >> 1, wc = wid & 1;
    int m0 = blockIdx.y * 128, n0 = blockIdx.x * 128;
    f32x4 acc[4][4] = {};
    int kt = Ksz >> 5;
    for (int kk = 0; kk < kt; kk++) {
        int k0 = kk << 5;
#pragma unroll
        for (int it = 0; it < 2; it++) {
            int ch = wid * 128 + it * 64 + lane;
            int row = ch >> 2, ko = (ch & 3) << 3;
            gload_lds16(A + (size_t)(m0 + row) * Ksz + k0 + ko, &sA[ch * 8]);
            gload_lds16(Bt + (size_t)(n0 + row) * Ksz + k0 + ko, &sB[ch * 8]);
        }
        __syncthreads();
        bf16x8 aF[4], bF[4];
#pragma unroll
        for (int i = 0; i < 4; i++)
            aF[i] = *(const bf16x8*)&sA[(wr * 64 + i * 16 + (lane & 15)) * 32 + ((lane >> 4) << 3)];
#pragma unroll
        for (int j = 0; j < 4; j++)
            bF[j] = *(const bf16x8*)&sB[(wc * 64 + j * 16 + (lane & 15)) * 32 + ((lane >> 4) << 3)];
#pragma unroll
        for (int i = 0; i < 4; i++)
#pragma unroll
            for (int j = 0; j < 4; j++)
                acc[i][j] = __builtin_amdgcn_mfma_f32_16x16x32_bf16(aF[i], bF[j], acc[i][j], 0, 0, 0);
        __syncthreads();
    }
    int cq = lane >> 4, cc = lane & 15;
#pragma unroll
    for (int i = 0; i < 4; i++)
#pragma unroll
        for (int j = 0; j < 4; j++) {
            int col = n0 + wc * 64 + j * 16 + cc;
            float bv = bias[col];
#pragma unroll
            for (int r = 0; r < 4; r++) {
                int row = m0 + wr * 64 + i * 16 + cq * 4 + r;
                float v = acc[i][j][r] + bv;
                if (RELU) v = fmaxf(v, 0.f);
                if (OUT_BF) Cb[(size_t)row * Nsz + col] = f2b(v);
                else        Cf[(size_t)row * Nsz + col] = v;
            }
        }
}

// ---------------- batched scores = (Q_bh @ K_bh^T) / 8 --------------
// q,k: [B*S, D] bf16, head slice via column offset. out fp32 [BH,S,S].
__global__ void gemm_scores(const unsigned short* __restrict__ q,
                            const unsigned short* __restrict__ k,
                            float* __restrict__ attn) {
    __shared__ unsigned short sA[128 * 32];
    __shared__ unsigned short sB[128 * 32];
    int tid = threadIdx.x, lane = tid & 63, wid = tid >> 6;
    int wr = wid >> 1, wc = wid & 1;
    int z = blockIdx.z, b = z >> 4, h = z & 15;
    const unsigned short* Ab = q + (size_t)b * SEQ * D_MODEL + h * DKH;
    const unsigned short* Bb = k + (size_t)b * SEQ * D_MODEL + h * DKH;
    float* C = attn + (size_t)z * SEQ * SEQ;
    int m0 = blockIdx.y * 128, n0 = blockIdx.x * 128;
    f32x4 acc[4][4] = {};
#pragma unroll
    for (int kk = 0; kk < 2; kk++) {
        int k0 = kk << 5;
#pragma unroll
        for (int it = 0; it < 2; it++) {
            int ch = wid * 128 + it * 64 + lane;
            int row = ch >> 2, ko = (ch & 3) << 3;
            gload_lds16(Ab + (size_t)(m0 + row) * D_MODEL + k0 + ko, &sA[ch * 8]);
            gload_lds16(Bb + (size_t)(n0 + row) * D_MODEL + k0 + ko, &sB[ch * 8]);
        }
        __syncthreads();
        bf16x8 aF[4], bF[4];
#pragma unroll
        for (int i = 0; i < 4; i++)
            aF[i] = *(const bf16x8*)&sA[(wr * 64 + i * 16 + (lane & 15)) * 32 + ((lane >> 4) << 3)];
#pragma unroll
        for (int j = 0; j < 4; j++)
            bF[j] = *(const bf16x8*)&sB[(wc * 64 + j * 16 + (lane & 15)) * 32 + ((lane >> 4) << 3)];
#pragma unroll
        for (int i = 0; i < 4; i++)
#pragma unroll
            for (int j = 0; j < 4; j++)
                acc[i][j] = __builtin_amdgcn_mfma_f32_16x16x32_bf16(aF[i], bF[j], acc[i][j], 0, 0, 0);
        __syncthreads();
    }
    int cq = lane >> 4, cc = lane & 15;
#pragma unroll
    for (int i = 0; i < 4; i++)
#pragma unroll
        for (int j = 0; j < 4; j++)
#pragma unroll
            for (int r = 0; r < 4; r++) {
                int row = m0 + wr * 64 + i * 16 + cq * 4 + r;
                int col = n0 + wc * 64 + j * 16 + cc;
                C[(size_t)row * SEQ + col] = acc[i][j][r] * 0.125f;
            }
}

// ---------------- in-place row softmax over SEQ fp32 ----------------
__global__ void softmax_rows(float* __restrict__ attn) {
    int wid = threadIdx.x >> 6, lane = threadIdx.x & 63;
    size_t r = (size_t)blockIdx.x * 4 + wid;
    float* p = attn + r * SEQ;
    float4 v[8];
    float m = -1e30f;
#pragma unroll
    for (int i = 0; i < 8; i++) {
        v[i] = ((const float4*)p)[lane + i * 64];
        m = fmaxf(m, fmaxf(fmaxf(v[i].x, v[i].y), fmaxf(v[i].z, v[i].w)));
    }
#pragma unroll
    for (int o = 32; o >= 1; o >>= 1) m = fmaxf(m, __shfl_xor(m, o));
    float s = 0.f;
#pragma unroll
    for (int i = 0; i < 8; i++) {
        v[i].x = __expf(v[i].x - m); v[i].y = __expf(v[i].y - m);
        v[i].z = __expf(v[i].z - m); v[i].w = __expf(v[i].w - m);
        s += v[i].x + v[i].y + v[i].z + v[i].w;
    }
#pragma unroll
    for (int o = 32; o >= 1; o >>= 1) s += __shfl_xor(s, o);
    float inv = 1.f / s;
#pragma unroll
    for (int i = 0; i < 8; i++) {
        v[i].x *= inv; v[i].y *= inv; v[i].z *= inv; v[i].w *= inv;
        ((float4*)p)[lane + i * 64] = v[i];
    }
}

// ---------------- ctx = attn(fp32, from d_out) @ V ------------------
// A: attn [BH,S,S] fp32 (converted to bf16 during staging).
// Bt: vt [BH][DKH][S] bf16. Out: ctx [B*S, D] bf16 at head col offset.
__global__ void gemm_ctx(const float* __restrict__ attn,
                         const unsigned short* __restrict__ vt,
                         unsigned short* __restrict__ ctx) {
    __shared__ unsigned short sA[128 * 32];
    __shared__ unsigned short sB[64 * 32];
    int tid = threadIdx.x, lane = tid & 63, wid = tid >> 6;
    int z = blockIdx.y, b = z >> 4, h = z & 15;
    const float* Ab = attn + (size_t)z * SEQ * SEQ;
    const unsigned short* Bb = vt + (size_t)z * DKH * SEQ;
    int m0 = blockIdx.x * 128;
    f32x4 acc[2][4] = {};
    for (int kk = 0; kk < SEQ / 32; kk++) {
        int k0 = kk << 5;
#pragma unroll
        for (int it = 0; it < 4; it++) {
            int p = (tid + it * 256) * 4;
            int row = p >> 5, col = p & 31;
            float4 f = *(const float4*)&Ab[(size_t)(m0 + row) * SEQ + k0 + col];
            ushort4 o; o.x = f2b(f.x); o.y = f2b(f.y); o.z = f2b(f.z); o.w = f2b(f.w);
            *(ushort4*)&sA[p] = o;
        }
        {
            int row = tid >> 2, ko = (tid & 3) << 3;
            gload_lds16(Bb + (size_t)row * SEQ + k0 + ko, &sB[tid * 8]);
        }
        __syncthreads();
        bf16x8 aF[2], bF[4];
#pragma unroll
        for (int i = 0; i < 2; i++)
            aF[i] = *(const bf16x8*)&sA[(wid * 32 + i * 16 + (lane & 15)) * 32 + ((lane >> 4) << 3)];
#pragma unroll
        for (int j = 0; j < 4; j++)
            bF[j] = *(const bf16x8*)&sB[(j * 16 + (lane & 15)) * 32 + ((lane >> 4) << 3)];
#pragma unroll
        for (int i = 0; i < 2; i++)
#pragma unroll
            for (int j = 0; j < 4; j++)
                acc[i][j] = __builtin_amdgcn_mfma_f32_16x16x32_bf16(aF[i], bF[j], acc[i][j], 0, 0, 0);
        __syncthreads();
    }
    int cq = lane >> 4, cc = lane & 15;
#pragma unroll
    for (int i = 0; i < 2; i++)
#pragma unroll
        for (int j = 0; j < 4; j++)
#pragma unroll
            for (int r = 0; r < 4; r++) {
                int mrow = m0 + wid * 32 + i * 16 + cq * 4 + r;
                int col = j * 16 + cc;
                ctx[(size_t)(b * SEQ + mrow) * D_MODEL + h * DKH + col] = f2b(acc[i][j][r]);
            }
}

// ---------------- fused residual add + LayerNorm --------------------
template<bool WRITE_BF>
__global__ void add_ln(const float* __restrict__ a, const float* __restrict__ res,
                       const float* __restrict__ g, const float* __restrict__ be,
                       float* __restrict__ outF, unsigned short* __restrict__ outB) {
    __shared__ float red[2][4];
    int row = blockIdx.x, t = threadIdx.x;
    float4 a4 = ((const float4*)(a + (size_t)row * D_MODEL))[t];
    float4 r4 = ((const float4*)(res + (size_t)row * D_MODEL))[t];
    float4 x; x.x = a4.x + r4.x; x.y = a4.y + r4.y; x.z = a4.z + r4.z; x.w = a4.w + r4.w;
    float s = x.x + x.y + x.z + x.w;
    float s2 = x.x * x.x + x.y * x.y + x.z * x.z + x.w * x.w;
#pragma unroll
    for (int o = 32; o >= 1; o >>= 1) { s += __shfl_down(s, o); s2 += __shfl_down(s2, o); }
    int wid = t >> 6, lane = t & 63;
    if (lane == 0) { red[0][wid] = s; red[1][wid] = s2; }
    __syncthreads();
    s = red[0][0] + red[0][1] + red[0][2] + red[0][3];
    s2 = red[1][0] + red[1][1] + red[1][2] + red[1][3];
    float mu = s * (1.f / D_MODEL);
    float var = s2 * (1.f / D_MODEL) - mu * mu;
    float rs = rsqrtf(var + LN_EPS);
    float4 g4 = ((const float4*)g)[t];
    float4 b4 = ((const float4*)be)[t];
    float4 y;
    y.x = (x.x - mu) * rs * g4.x + b4.x;
    y.y = (x.y - mu) * rs * g4.y + b4.y;
    y.z = (x.z - mu) * rs * g4.z + b4.z;
    y.w = (x.w - mu) * rs * g4.w + b4.w;
    ((float4*)(outF + (size_t)row * D_MODEL))[t] = y;
    if (WRITE_BF) {
        ushort4 o; o.x = f2b(y.x); o.y = f2b(y.y); o.z = f2b(y.z); o.w = f2b(y.w);
        ((ushort4*)(outB + (size_t)row * D_MODEL))[t] = o;
    }
}

extern "C" void kernel_launch(void* const* d_in, const int* in_sizes, int n_in,
                              void* d_out, int out_size, void* d_ws, size_t ws_size,
                              hipStream_t stream) {
    const float* src = (const float*)d_in[0];
    const float* wq = (const float*)d_in[1];  const float* bq = (const float*)d_in[2];
    const float* wk = (const float*)d_in[3];  const float* bk = (const float*)d_in[4];
    const float* wv = (const float*)d_in[5];  const float* bv = (const float*)d_in[6];
    const float* wo = (const float*)d_in[7];  const float* bo = (const float*)d_in[8];
    const float* w1 = (const float*)d_in[9];  const float* b1 = (const float*)d_in[10];
    const float* w2 = (const float*)d_in[11]; const float* b2 = (const float*)d_in[12];
    const float* g1 = (const float*)d_in[13]; const float* be1 = (const float*)d_in[14];
    const float* g2 = (const float*)d_in[15]; const float* be2 = (const float*)d_in[16];

    float* outF = (float*)d_out;
    float* attn = outF + (size_t)MROWS * D_MODEL; // [BH, S, S] fp32

    // ---- workspace layout (bump allocator, 256B aligned) ----
    char* ws = (char*)d_ws;
    size_t off = 0;
    auto alloc = [&](size_t bytes) -> char* {
        char* p = ws + off;
        off = (off + bytes + 255) & ~(size_t)255;
        return p;
    };
    unsigned short* src_bf = (unsigned short*)alloc((size_t)MROWS * D_MODEL * 2);
    unsigned short* wqT = (unsigned short*)alloc((size_t)D_MODEL * D_MODEL * 2);
    unsigned short* wkT = (unsigned short*)alloc((size_t)D_MODEL * D_MODEL * 2);
    unsigned short* wvT = (unsigned short*)alloc((size_t)D_MODEL * D_MODEL * 2);
    unsigned short* woT = (unsigned short*)alloc((size_t)D_MODEL * D_MODEL * 2);
    unsigned short* w1T = (unsigned short*)alloc((size_t)D_FF * D_MODEL * 2);
    unsigned short* w2T = (unsigned short*)alloc((size_t)D_MODEL * D_FF * 2);
    unsigned short* qb  = (unsigned short*)alloc((size_t)MROWS * D_MODEL * 2);
    unsigned short* kb  = (unsigned short*)alloc((size_t)MROWS * D_MODEL * 2);
    unsigned short* vb  = (unsigned short*)alloc((size_t)MROWS * D_MODEL * 2);
    unsigned short* vt  = (unsigned short*)alloc((size_t)BHT * DKH * SEQ * 2);
    unsigned short* ctxb = (unsigned short*)alloc((size_t)MROWS * D_MODEL * 2);
    float* attn_out = (float*)alloc((size_t)MROWS * D_MODEL * 4);
    float* xf = (float*)alloc((size_t)MROWS * D_MODEL * 4);
    unsigned short* xb = (unsigned short*)alloc((size_t)MROWS * D_MODEL * 2);
    unsigned short* h1 = (unsigned short*)alloc((size_t)MROWS * D_FF * 2);
    float* h2 = (float*)alloc((size_t)MROWS * D_MODEL * 4);
    (void)ws_size; (void)in_sizes; (void)n_in; (void)out_size;

    // 1. activations + weights -> bf16 (weights transposed to [N,K])
    cvt_f32_bf16<<<(MROWS * D_MODEL / 4 + 255) / 256, 256, 0, stream>>>(src, src_bf, MROWS * D_MODEL / 4);
    dim3 trg(D_MODEL / 32, D_MODEL / 32);
    tr_f32_bf16<<<trg, 256, 0, stream>>>(wq, wqT, D_MODEL, D_MODEL);
    tr_f32_bf16<<<trg, 256, 0, stream>>>(wk, wkT, D_MODEL, D_MODEL);
    tr_f32_bf16<<<trg, 256, 0, stream>>>(wv, wvT, D_MODEL, D_MODEL);
    tr_f32_bf16<<<trg, 256, 0, stream>>>(wo, woT, D_MODEL, D_MODEL);
    tr_f32_bf16<<<dim3(D_FF / 32, D_MODEL / 32), 256, 0, stream>>>(w1, w1T, D_MODEL, D_FF);
    tr_f32_bf16<<<dim3(D_MODEL / 32, D_FF / 32), 256, 0, stream>>>(w2, w2T, D_FF, D_MODEL);

    // 2. QKV projections
    dim3 gq(D_MODEL / 128, MROWS / 128);
    gemm_bf16<true, false><<<gq, 256, 0, stream>>>(src_bf, wqT, bq, nullptr, qb, MROWS, D_MODEL, D_MODEL);
    gemm_bf16<true, false><<<gq, 256, 0, stream>>>(src_bf, wkT, bk, nullptr, kb, MROWS, D_MODEL, D_MODEL);
    gemm_bf16<true, false><<<gq, 256, 0, stream>>>(src_bf, wvT, bv, nullptr, vb, MROWS, D_MODEL, D_MODEL);
    tr_v<<<dim3(D_MODEL / 32, SEQ / 32, BATCH), 256, 0, stream>>>(vb, vt);

    // 3. attention: scores -> softmax (in d_out) -> ctx
    gemm_scores<<<dim3(SEQ / 128, SEQ / 128, BHT), 256, 0, stream>>>(qb, kb, attn);
    softmax_rows<<<BHT * SEQ / 4, 256, 0, stream>>>(attn);
    gemm_ctx<<<dim3(SEQ / 128, BHT), 256, 0, stream>>>(attn, vt, ctxb);

    // 4. out-proj + LN1
    gemm_bf16<false, false><<<gq, 256, 0, stream>>>(ctxb, woT, bo, attn_out, nullptr, MROWS, D_MODEL, D_MODEL);
    add_ln<true><<<MROWS, 256, 0, stream>>>(src, attn_out, g1, be1, xf, xb);

    // 5. FFN + LN2
    gemm_bf16<true, true><<<dim3(D_FF / 128, MROWS / 128), 256, 0, stream>>>(xb, w1T, b1, nullptr, h1, MROWS, D_FF, D_MODEL);
    gemm_bf16<false, false><<<gq, 256, 0, stream>>>(h1, w2T, b2, h2, nullptr, MROWS, D_MODEL, D_FF);
    add_ln<false><<<MROWS, 256, 0, stream>>>(xf, h2, g2, be2, outF, nullptr);
}